// Round 13
// baseline (170.762 us; speedup 1.0000x reference)
//
#include <hip/hip_runtime.h>
#include <cstdint>
#include <cfloat>

// Problem constants (Memcodes): B=2, N=4096, H=16, D=64, C=1024
#define B_ 2
#define N_ 4096
#define H_ 16
#define D_ 64
#define C_ 1024

#define TI 64      // query rows per tile block (1 row-group per wave)
#define CJ 32      // codebook rows staged per chunk (dbuf = 16384 B)
#define EPS 4e-3f  // near-tie flag: covers split err 5e-5 + pack-quant ~1e-3

typedef unsigned short u16;
typedef unsigned int   u32;
typedef __attribute__((ext_vector_type(8))) short short8;  // 8 bf16 (4 VGPRs)
typedef __attribute__((ext_vector_type(4))) float f32x4;

__device__ __forceinline__ float bf2f(u16 s) {
    u32 u = ((u32)s) << 16;
    return __uint_as_float(u);
}
// round-to-nearest-even f32 -> bf16
__device__ __forceinline__ u16 f2bf(float f) {
    u32 u = __float_as_uint(f);
    return (u16)((u + 0x7fffu + ((u >> 16) & 1u)) >> 16);
}
// descending compare-exchange on plain floats (index packed in low bits)
__device__ __forceinline__ void cf(float& a, float& b) {
    float t = fmaxf(a, b);
    b = fminf(a, b);
    a = t;
}
// scale by 1/8 (exact) then bf16-split a float4 pair into hi/lo short8
// (bit-identical to the LDS-staged split; verified absmax=0.0 in R9/R10)
__device__ __forceinline__ void split8(float4 a, float4 b, short8& hi, short8& lo) {
    float v0 = a.x * 0.125f, v1 = a.y * 0.125f, v2 = a.z * 0.125f, v3 = a.w * 0.125f;
    float v4 = b.x * 0.125f, v5 = b.y * 0.125f, v6 = b.z * 0.125f, v7 = b.w * 0.125f;
    u16 h0 = f2bf(v0), h1 = f2bf(v1), h2 = f2bf(v2), h3 = f2bf(v3);
    u16 h4 = f2bf(v4), h5 = f2bf(v5), h6 = f2bf(v6), h7 = f2bf(v7);
    short8 h8, l8;
    h8[0] = (short)h0; h8[1] = (short)h1; h8[2] = (short)h2; h8[3] = (short)h3;
    h8[4] = (short)h4; h8[5] = (short)h5; h8[6] = (short)h6; h8[7] = (short)h7;
    l8[0] = (short)f2bf(v0 - bf2f(h0)); l8[1] = (short)f2bf(v1 - bf2f(h1));
    l8[2] = (short)f2bf(v2 - bf2f(h2)); l8[3] = (short)f2bf(v3 - bf2f(h3));
    l8[4] = (short)f2bf(v4 - bf2f(h4)); l8[5] = (short)f2bf(v5 - bf2f(h5));
    l8[6] = (short)f2bf(v6 - bf2f(h6)); l8[7] = (short)f2bf(v7 - bf2f(h7));
    hi = h8; lo = l8;
}
// async 16B global->LDS copy (HW writes lds_base + lane*16)
__device__ __forceinline__ void gll16(const u16* g, u16* l) {
    __builtin_amdgcn_global_load_lds(
        (const __attribute__((address_space(1))) void*)g,
        (__attribute__((address_space(3))) void*)l, 16, 0, 0);
}

// ---------------------------------------------------------------------------
// K1: per-head projections of the codebooks (fp32, ascending-d FMA chain ==
// numpy einsum order; k32 stays np-bit-exact). Also emits bf16 split of k.
// No-LDS register version (R6-verified). Blocks with jc==0 zero this head's
// ghist slice (refine phase runs strictly after proj).
// ---------------------------------------------------------------------------
__global__ __launch_bounds__(256, 2)
void proj_kernel(const float* __restrict__ cb,
                 const float* __restrict__ wk,
                 const float* __restrict__ wv,
                 float* __restrict__ k32,
                 float* __restrict__ v32,
                 u16* __restrict__ khi,
                 u16* __restrict__ klo,
                 u32* __restrict__ ghist) {
    int h  = blockIdx.x >> 5;
    int jc = blockIdx.x & 31;
    int tid = threadIdx.x;
    int wid  = tid >> 6;
    int lane = tid & 63;

    if (jc == 0) {
        ghist[h * C_ + tid]       = 0u;
        ghist[h * C_ + tid + 256] = 0u;
        ghist[h * C_ + tid + 512] = 0u;
        ghist[h * C_ + tid + 768] = 0u;
    }

    // per-thread wk/wv column (column index = lane). Coalesced: for fixed d,
    // the 64 lanes read 256 consecutive bytes. L2-hot across 32 blocks/head.
    const float* wkh = wk + (size_t)h * D_ * D_ + lane;
    const float* wvh = wv + (size_t)h * D_ * D_ + lane;
    float wkc[D_], wvc[D_];
#pragma unroll
    for (int d = 0; d < D_; ++d) {
        wkc[d] = wkh[(size_t)d * D_];
        wvc[d] = wvh[(size_t)d * D_];
    }

#pragma unroll 1
    for (int i = 0; i < 8; ++i) {
        int jl  = wid * 8 + i;
        int row = jc * 32 + jl;
        // lane d holds cb[row][d]; broadcast via readlane (uniform SGPR)
        float cv = cb[((size_t)h * C_ + row) * D_ + lane];
        float ak = 0.f, av = 0.f;
#pragma unroll
        for (int d = 0; d < D_; ++d) {
            float s = __int_as_float(__builtin_amdgcn_readlane(__float_as_int(cv), d));
            ak = fmaf(s, wkc[d], ak);
            av = fmaf(s, wvc[d], av);
        }
        size_t o = ((size_t)h * C_ + row) * D_ + lane;
        k32[o] = ak;
        v32[o] = av;
        u16 hi = f2bf(ak);
        khi[o] = hi;
        klo[o] = f2bf(ak - bf2f(hi));
    }
}

// ---------------------------------------------------------------------------
// K2: MFMA tile pass + fused refine/outputs.
// THIS REVISION (grid-cap removal): TI=64 -> 2048 blocks = 8 blocks/CU
// (R10 proved resources allowed 8 but the 1024-block grid capped at 4;
// R12 proved staging/LDS were never the limiter -> the loop is sync/latency
// bound and needs more resident blocks). Per block: 4 waves, wave w owns
// rows w*16..w*16+15 (ONE row-group); A-frags bf16-split directly from x
// (R9/R10-verified bit-exact); k staged via width-16 global_load_lds with
// the R12-verified both-sides granule XOR-swizzle; CJ=32 double-buffered in
// 16384 B LDS. VGPR target <=64 (no min-wave pin — R9 lesson) so occupancy
// derives to 8 blocks/CU. One barrier per chunk; serial fused-refine
// epilogue verbatim (R7/R12). All arithmetic chains unchanged -> absmax 0.
// ---------------------------------------------------------------------------
__global__ __launch_bounds__(256, 4)
void tile_kernel(const float* __restrict__ x,
                 const u16* __restrict__ khi,
                 const u16* __restrict__ klo,
                 const float* __restrict__ k32,
                 const float* __restrict__ v32,
                 u32* __restrict__ ghist,
                 float* __restrict__ out,
                 float* __restrict__ idx_out) {
    // k dbuf: buf p at smem + p*4096 u16 (hi 2048 u16, lo at +2048). 16384 B.
    __shared__ __align__(16) u16 smem[2 * 4096];

    int blk = blockIdx.x;
    int it = blk & 63;             // N_/TI = 64 tiles per (b,h)
    int bh = blk >> 6;
    int h = bh & (H_ - 1);
    int b = bh >> 4;
    int i0 = it * TI;
    int tid = threadIdx.x;
    int w    = tid >> 6;
    int lane = tid & 63;
    int lm   = lane & 15;
    int lq   = lane >> 4;
    int rowbase = (b * H_ + h) * N_ + i0;

    const u16* khg = khi + (size_t)h * C_ * D_;
    const u16* klg = klo + (size_t)h * C_ * D_;

    // ---- staging geometry: per chunk 8 segments of 1024 B (4 hi + 4 lo);
    // wave 0/1 -> hi, wave 2/3 -> lo; 2 segments per wave. Segment s covers
    // chunk rows s*8..s*8+8. Per-lane source: row rl=lane>>3, granule
    // cc=lane&7 reads global granule cc^rl (pre-swizzle); HW writes LDS
    // linearly at base+lane*16. (R12-verified mapping.)
    int rl = lane >> 3, cc = lane & 7;
    int swz = rl * 64 + ((cc ^ rl) * 8);   // u16 offset within a segment
    const u16* srcb = (w < 2) ? khg : klg;
    int segl = (w & 1) * 2;                // first segment for this wave
    int dhalf = (w < 2) ? 0 : 2048;        // u16 offset of lo within a buffer

    // ---- prologue: async-stage chunk 0 into buffer 0 ----
    {
        const u16* s0 = srcb + swz;
        u16* d0 = smem + dhalf;
#pragma unroll
        for (int i = 0; i < 2; ++i)
            gll16(s0 + (segl + i) * 512, d0 + (segl + i) * 512);
    }

    // ---- A-frags straight from x into registers (1 row-group).
    // lane (lm,lq): row = i0 + w*16 + lm, k-elems lq*8..+7 and 32+lq*8..+7.
    short8 ahi0, ahi1, alo0, alo1;
    {
        int row = i0 + w * 16 + lm;
        const float* xr = x + ((size_t)(b * N_ + row)) * (H_ * D_) + h * D_ + lq * 8;
        float4 q0 = *(const float4*)(xr);
        float4 q1 = *(const float4*)(xr + 4);
        float4 q2 = *(const float4*)(xr + 32);
        float4 q3 = *(const float4*)(xr + 36);
        split8(q0, q1, ahi0, alo0);
        split8(q2, q3, ahi1, alo1);
    }

    float b1[4], b2[4];
#pragma unroll
    for (int r = 0; r < 4; ++r) { b1[r] = -FLT_MAX; b2[r] = -FLT_MAX; }

    __syncthreads();   // chunk 0 staged (drains vmcnt incl. A-frag loads)

#pragma unroll 1
    for (int ch = 0; ch < C_ / CJ; ++ch) {     // 32 chunks of 32 codes
        // ---- async-issue next chunk's staging EARLY (drains at barrier) ----
        bool pf = (ch + 1 < C_ / CJ);
        if (pf) {
            const u16* s1 = srcb + (size_t)(ch + 1) * CJ * D_ + swz;
            u16* d1 = smem + ((ch + 1) & 1) * 4096 + dhalf;
#pragma unroll
            for (int i = 0; i < 2; ++i)
                gll16(s1 + (segl + i) * 512, d1 + (segl + i) * 512);
        }

        const u16* khc = smem + (ch & 1) * 4096;
        const u16* klc = khc + 2048;
        int jb = ch * CJ;

#pragma unroll
        for (int t = 0; t < 2; ++t) {      // 2 j-tiles of 16 cols
            int row  = t * 16 + lm;
            int base = row * 64;
            int g0   = (lq ^ (lm & 7)) * 8;         // swizzled granule, frag0
            int g1   = ((lq + 4) ^ (lm & 7)) * 8;   // swizzled granule, frag1
            short8 bh0 = *(const short8*)&khc[base + g0];
            short8 bh1 = *(const short8*)&khc[base + g1];
            short8 bl0 = *(const short8*)&klc[base + g0];
            short8 bl1 = *(const short8*)&klc[base + g1];
            int rj = 1023 - (jb + t * 16 + lm);   // index packed desc

            f32x4 acc = {0.f, 0.f, 0.f, 0.f};
            acc = __builtin_amdgcn_mfma_f32_16x16x32_bf16(ahi0, bh0, acc, 0, 0, 0);
            acc = __builtin_amdgcn_mfma_f32_16x16x32_bf16(ahi1, bh1, acc, 0, 0, 0);
            acc = __builtin_amdgcn_mfma_f32_16x16x32_bf16(ahi0, bl0, acc, 0, 0, 0);
            acc = __builtin_amdgcn_mfma_f32_16x16x32_bf16(ahi1, bl1, acc, 0, 0, 0);
            acc = __builtin_amdgcn_mfma_f32_16x16x32_bf16(alo0, bh0, acc, 0, 0, 0);
            acc = __builtin_amdgcn_mfma_f32_16x16x32_bf16(alo1, bh1, acc, 0, 0, 0);
#pragma unroll
            for (int r = 0; r < 4; ++r) {
                int pb = (__float_as_int(acc[r]) & 0xFFFFFC00) | rj;
                float pv = __int_as_float(pb);
                // top-2 update; invariant b1>=b2, no NaNs -> med3 is exact
                b2[r] = __builtin_amdgcn_fmed3f(pv, b1[r], b2[r]);
                b1[r] = fmaxf(pv, b1[r]);
            }
        }

        __syncthreads();   // drains the async staging queue (vmcnt) + barrier
    }

    // ---- epilogue scratch in LDS (overlays buf0; chunk 31 lived in buf1) ----
    float* rv_f = (float*)smem;            // [TI][4] packed top-4 values
    int*   rj_i = (int*)(rv_f + TI * 4);   // [TI][4] decoded indices
    float* idxv = (float*)(rj_i + TI * 4); // [TI]
    float* sc_s = idxv + TI;               // [4]

    // ---- merge top-2 across the 16 lm-lanes -> row top-4, store to LDS ----
#pragma unroll
    for (int r = 0; r < 4; ++r) {
        float e0 = b1[r], e1 = b2[r], e2 = -FLT_MAX, e3 = -FLT_MAX;
#pragma unroll
        for (int off = 1; off < 16; off <<= 1) {
            float e7 = __shfl_xor(e0, off, 16);
            float e6 = __shfl_xor(e1, off, 16);
            float e5 = __shfl_xor(e2, off, 16);
            float e4 = __shfl_xor(e3, off, 16);
            cf(e0, e4); cf(e1, e5); cf(e2, e6); cf(e3, e7);
            cf(e0, e2); cf(e1, e3); cf(e0, e1); cf(e2, e3);
        }
        if (lm == 0) {
            int rl2 = w * 16 + lq * 4 + r;
            int j0 = 1023 - (__float_as_int(e0) & 1023);
            rv_f[rl2 * 4 + 0] = e0; rj_i[rl2 * 4 + 0] = j0;
            rv_f[rl2 * 4 + 1] = e1; rj_i[rl2 * 4 + 1] = 1023 - (__float_as_int(e1) & 1023);
            rv_f[rl2 * 4 + 2] = e2; rj_i[rl2 * 4 + 2] = 1023 - (__float_as_int(e2) & 1023);
            rv_f[rl2 * 4 + 3] = e3; rj_i[rl2 * 4 + 3] = 1023 - (__float_as_int(e3) & 1023);
            idxv[rl2] = (float)(j0 & (C_ - 1));
        }
    }
    __syncthreads();

    // ---- fused refine: numpy-fp32-emulated near-tie re-decision (verbatim
    // R5/R7 logic: AVX512 16-lane accumulator, 4-unrolled chained FMA (chunk
    // order 3,2,1,0), _mm512_reduce_add_ps butterfly (strides 8,4,2,1)) ----
#pragma unroll 1
    for (int r = 0; r < TI; ++r) {
        float v0 = rv_f[r * 4 + 0];
        int nc = 1;
        while (nc < 4 && v0 - rv_f[r * 4 + nc] < EPS) ++nc;   // uniform across block
        if (nc == 1) continue;
        int wq = tid >> 6;
        int ln = tid & 63;
        if (wq < nc) {
            int j = rj_i[r * 4 + wq] & (C_ - 1);
            float qv = x[((size_t)(b * N_ + i0 + r)) * (H_ * D_) + h * D_ + ln] * 0.125f;
            float kv = k32[((size_t)h * C_ + j) * D_ + ln];
            float a2 = 0.f;
#pragma unroll
            for (int c = 3; c >= 0; --c) {
                float qq = __shfl(qv, (ln & 15) + c * 16, 64);
                float kk = __shfl(kv, (ln & 15) + c * 16, 64);
                a2 = fmaf(qq, kk, a2);
            }
#pragma unroll
            for (int off2 = 8; off2 >= 1; off2 >>= 1)
                a2 += __shfl_xor(a2, off2, 16);
            if (ln == 0) sc_s[wq] = a2;
        }
        __syncthreads();
        if (tid == 0) {
            float bs = sc_s[0]; int bj = rj_i[r * 4 + 0] & (C_ - 1);
            float ss = -FLT_MAX; int sj = bj;
            for (int k2 = 1; k2 < nc; ++k2) {
                float s = sc_s[k2]; int j = rj_i[r * 4 + k2] & (C_ - 1);
                if (s > bs || (s == bs && j < bj)) { ss = bs; sj = bj; bs = s; bj = j; }
                else if (s > ss || (s == ss && j < sj)) { ss = s; sj = j; }
            }
            rj_i[r * 4 + 0] = bj;
            float outv = (float)bj;
            int dj = bj > sj ? bj - sj : sj - bj;
            if (bs - ss < 1e-6f && dj <= 36 && dj > 0) outv = 0.5f * (float)(bj + sj);
            idxv[r] = outv;
        }
        __syncthreads();
    }
    __syncthreads();

    // ---- idx out + fused per-head histogram (same bucketing as perp) ----
    if (tid < TI) {
        float iv = idxv[tid];
        idx_out[(size_t)rowbase + tid] = iv;
        atomicAdd(&ghist[h * C_ + (((int)(iv + 0.25f)) & (C_ - 1))], 1u);
    }

    // ---- one-hot value gather -> out ----
    const float* vh = v32 + (size_t)h * C_ * D_;
    float* ob = out + ((size_t)(b * N_ + i0) * (H_ * D_)) + h * D_;
#pragma unroll
    for (int r = 0; r < TI / 4; ++r) {     // 16 iters: 4 rows per iteration
        int f   = tid + 256 * r;
        int row = f >> 6;
        int d   = f & 63;
        int bi  = rj_i[row * 4 + 0] & (C_ - 1);
        ob[(size_t)row * (H_ * D_) + d] = vh[(size_t)bi * D_ + d];
    }
}

// ---------------------------------------------------------------------------
// K3: perplexity per head from the fused global histogram. Same accumulation
// order (i = tid step 256) and same reduction tree as the verified version —
// counts are identical, so the result is bit-identical.
// ---------------------------------------------------------------------------
__global__ __launch_bounds__(256)
void perp_kernel(const u32* __restrict__ ghist, float* __restrict__ perp_out) {
    __shared__ float red[256];
    int h = blockIdx.x;
    int tid = threadIdx.x;

    float s = 0.f;
    for (int i = tid; i < C_; i += 256) {
        float p = (float)ghist[h * C_ + i] * (1.0f / (B_ * N_));
        s += p * logf(p + 1e-10f);
    }
    red[tid] = s;
    __syncthreads();
    for (int st = 128; st > 0; st >>= 1) {
        if (tid < st) red[tid] += red[tid + st];
        __syncthreads();
    }
    if (tid == 0) perp_out[h] = expf(-red[0]);
}

// ---------------------------------------------------------------------------
extern "C" void kernel_launch(void* const* d_in, const int* in_sizes, int n_in,
                              void* d_out, int out_size, void* d_ws, size_t ws_size,
                              hipStream_t stream) {
    (void)in_sizes; (void)n_in; (void)out_size; (void)ws_size;
    const float* x  = (const float*)d_in[0];   // (B, N, H*D) fp32
    const float* cb = (const float*)d_in[1];   // (H, C, D)   fp32
    const float* wk = (const float*)d_in[2];   // (H, D, D)   fp32
    const float* wv = (const float*)d_in[3];   // (H, D, D)   fp32

    // flat fp32 output buffer: [out | indices | perp]
    float* out      = (float*)d_out;                     // B*N*H*D
    float* idx_out  = out + (size_t)B_ * N_ * H_ * D_;   // B*H*N
    float* perp_out = idx_out + (size_t)B_ * H_ * N_;    // H

    // workspace: k32 4MiB | v32 4MiB | khi 2MiB | klo 2MiB | ghist 64KiB
    float* k32   = (float*)d_ws;
    float* v32   = k32 + (size_t)H_ * C_ * D_;
    u16*   khi   = (u16*)(v32 + (size_t)H_ * C_ * D_);
    u16*   klo   = khi + (size_t)H_ * C_ * D_;
    u32*   ghist = (u32*)(klo + (size_t)H_ * C_ * D_);

    proj_kernel<<<H_ * 32, 256, 0, stream>>>(cb, wk, wv, k32, v32, khi, klo, ghist);
    tile_kernel<<<B_ * H_ * (N_ / TI), 256, 0, stream>>>(x, khi, klo, k32, v32, ghist,
                                                         out, idx_out);
    perp_kernel<<<H_, 256, 0, stream>>>(ghist, perp_out);
}

// Round 14
// 162.034 us; speedup vs baseline: 1.0539x; 1.0539x over previous
//
#include <hip/hip_runtime.h>
#include <cstdint>
#include <cfloat>

// Problem constants (Memcodes): B=2, N=4096, H=16, D=64, C=1024
#define B_ 2
#define N_ 4096
#define H_ 16
#define D_ 64
#define C_ 1024

#define TI 128     // query rows per tile block
#define CJ 64      // codebook rows staged per chunk
#define QP 72      // padded LDS row stride in u16 (144 B, 16B-aligned rows)
#define EPS 4e-3f  // near-tie flag: covers split err 5e-5 + pack-quant ~1e-3

typedef unsigned short u16;
typedef unsigned int   u32;
typedef __attribute__((ext_vector_type(8))) short short8;  // 8 bf16 (4 VGPRs)
typedef __attribute__((ext_vector_type(4))) float f32x4;

__device__ __forceinline__ float bf2f(u16 s) {
    u32 u = ((u32)s) << 16;
    return __uint_as_float(u);
}
// round-to-nearest-even f32 -> bf16
__device__ __forceinline__ u16 f2bf(float f) {
    u32 u = __float_as_uint(f);
    return (u16)((u + 0x7fffu + ((u >> 16) & 1u)) >> 16);
}
// descending compare-exchange on plain floats (index packed in low bits)
__device__ __forceinline__ void cf(float& a, float& b) {
    float t = fmaxf(a, b);
    b = fminf(a, b);
    a = t;
}

// ---------------------------------------------------------------------------
// K1: per-head projections of the codebooks (fp32, ascending-d FMA chain ==
// numpy einsum order; k32 stays np-bit-exact). Also emits bf16 split of k.
// No-LDS register version (R6-verified). Blocks with jc==0 zero this head's
// ghist slice (refine phase runs strictly after proj).
// ---------------------------------------------------------------------------
__global__ __launch_bounds__(256, 2)
void proj_kernel(const float* __restrict__ cb,
                 const float* __restrict__ wk,
                 const float* __restrict__ wv,
                 float* __restrict__ k32,
                 float* __restrict__ v32,
                 u16* __restrict__ khi,
                 u16* __restrict__ klo,
                 u32* __restrict__ ghist) {
    int h  = blockIdx.x >> 5;
    int jc = blockIdx.x & 31;
    int tid = threadIdx.x;
    int wid  = tid >> 6;
    int lane = tid & 63;

    if (jc == 0) {
        ghist[h * C_ + tid]       = 0u;
        ghist[h * C_ + tid + 256] = 0u;
        ghist[h * C_ + tid + 512] = 0u;
        ghist[h * C_ + tid + 768] = 0u;
    }

    // per-thread wk/wv column (column index = lane). Coalesced: for fixed d,
    // the 64 lanes read 256 consecutive bytes. L2-hot across 32 blocks/head.
    const float* wkh = wk + (size_t)h * D_ * D_ + lane;
    const float* wvh = wv + (size_t)h * D_ * D_ + lane;
    float wkc[D_], wvc[D_];
#pragma unroll
    for (int d = 0; d < D_; ++d) {
        wkc[d] = wkh[(size_t)d * D_];
        wvc[d] = wvh[(size_t)d * D_];
    }

#pragma unroll 1
    for (int i = 0; i < 8; ++i) {
        int jl  = wid * 8 + i;
        int row = jc * 32 + jl;
        // lane d holds cb[row][d]; broadcast via readlane (uniform SGPR)
        float cv = cb[((size_t)h * C_ + row) * D_ + lane];
        float ak = 0.f, av = 0.f;
#pragma unroll
        for (int d = 0; d < D_; ++d) {
            float s = __int_as_float(__builtin_amdgcn_readlane(__float_as_int(cv), d));
            ak = fmaf(s, wkc[d], ak);
            av = fmaf(s, wvc[d], av);
        }
        size_t o = ((size_t)h * C_ + row) * D_ + lane;
        k32[o] = ak;
        v32[o] = av;
        u16 hi = f2bf(ak);
        khi[o] = hi;
        klo[o] = f2bf(ak - bf2f(hi));
    }
}

// ---------------------------------------------------------------------------
// K2: MFMA tile pass + FUSED refine/outputs. Block = (b, h, 128-row tile),
// 4 waves; wave w owns rows w*32..w*32+31 as two 16-row groups.
// Main loop: R5-verified structure (k dbuf in LDS, one barrier per chunk,
// early register prefetch, packed (value|index) top-2 -> row top-4).
// Epilogue: merge writes rv/rj/idxv into the (now free) LDS and the R5
// refine logic runs verbatim in-block: serial near-tie re-decision
// (identical DOT FMA order + selection compares), idx write, ghist atomic,
// and the v-gather out-write. (R7-verified session best: 162.7 us total.)
// ---------------------------------------------------------------------------
__global__ __launch_bounds__(256, 4)
void tile_kernel(const float* __restrict__ x,
                 const u16* __restrict__ khi,
                 const u16* __restrict__ klo,
                 const float* __restrict__ k32,
                 const float* __restrict__ v32,
                 u32* __restrict__ ghist,
                 float* __restrict__ out,
                 float* __restrict__ idx_out) {
    // phase 1: q hi/lo staging (TI*QP*2 u16 = 36864 B)
    // phase 2 (after A-frags in regs): double-buffered k chunks
    // phase 3 (epilogue): rv/rj/idxv/sc refine scratch (4.6 KB)
    __shared__ __align__(16) u16 smem[TI * QP * 2];
    u16* qhi_s = smem;
    u16* qlo_s = smem + TI * QP;
    const int HBUF = CJ * QP;          // 4608 u16 = 9216 B

    int blk = blockIdx.x;
    int it = blk & 31;             // N_/TI = 32 tiles per (b,h)
    int bh = blk >> 5;
    int h = bh & (H_ - 1);
    int b = bh >> 4;
    int i0 = it * TI;
    int tid = threadIdx.x;
    int w    = tid >> 6;
    int lane = tid & 63;
    int lm   = lane & 15;
    int lq   = lane >> 4;
    int rowbase = (b * H_ + h) * N_ + i0;

    // ---- stage q (scaled 1/8, exact) + bf16 split into LDS ----
    {
        const float* xb = x + ((size_t)(b * N_ + i0) * (H_ * D_)) + h * D_;
#pragma unroll
        for (int i = 0; i < 8; ++i) {
            int e4  = tid + 256 * i;       // float4 index 0..2047
            int row = e4 >> 4;
            int c4  = (e4 & 15) * 4;
            float4 v = *(const float4*)(xb + (size_t)row * (H_ * D_) + c4);
            v.x *= 0.125f; v.y *= 0.125f; v.z *= 0.125f; v.w *= 0.125f;
            u16 h0 = f2bf(v.x), h1 = f2bf(v.y), h2 = f2bf(v.z), h3 = f2bf(v.w);
            u16 l0 = f2bf(v.x - bf2f(h0)), l1 = f2bf(v.y - bf2f(h1));
            u16 l2 = f2bf(v.z - bf2f(h2)), l3 = f2bf(v.w - bf2f(h3));
            uint2 ph = make_uint2((u32)h0 | ((u32)h1 << 16), (u32)h2 | ((u32)h3 << 16));
            uint2 pl = make_uint2((u32)l0 | ((u32)l1 << 16), (u32)l2 | ((u32)l3 << 16));
            *(uint2*)&qhi_s[row * QP + c4] = ph;
            *(uint2*)&qlo_s[row * QP + c4] = pl;
        }
    }
    __syncthreads();

    // ---- A-frags to registers (2 row-groups), then q LDS becomes free ----
    short8 ahi[2][2], alo[2][2];
#pragma unroll
    for (int g = 0; g < 2; ++g) {
        int base = (w * 32 + g * 16 + lm) * QP;
        ahi[g][0] = *(const short8*)&qhi_s[base + lq * 8];
        ahi[g][1] = *(const short8*)&qhi_s[base + 32 + lq * 8];
        alo[g][0] = *(const short8*)&qlo_s[base + lq * 8];
        alo[g][1] = *(const short8*)&qlo_s[base + 32 + lq * 8];
    }
    __syncthreads();   // all waves done reading q before k overwrites smem

    float b1[2][4], b2[2][4];
#pragma unroll
    for (int g = 0; g < 2; ++g)
#pragma unroll
        for (int r = 0; r < 4; ++r) { b1[g][r] = -FLT_MAX; b2[g][r] = -FLT_MAX; }

    const u16* khg = khi + (size_t)h * C_ * D_;
    const u16* klg = klo + (size_t)h * C_ * D_;

    // per-thread staging slots (same for every chunk)
    int srow = tid >> 3;           // 0..31
    int sc8  = (tid & 7) * 8;      // u16 col offset

    // ---- prologue: stage chunk 0 into buffer 0 ----
    {
        const uint4* gh = (const uint4*)khg;
        const uint4* gl = (const uint4*)klg;
        uint4 a0 = gh[tid], a1 = gh[tid + 256];
        uint4 c0 = gl[tid], c1 = gl[tid + 256];
        *(uint4*)&smem[srow * QP + sc8]               = a0;
        *(uint4*)&smem[(srow + 32) * QP + sc8]        = a1;
        *(uint4*)&smem[HBUF + srow * QP + sc8]        = c0;
        *(uint4*)&smem[HBUF + (srow + 32) * QP + sc8] = c1;
    }
    __syncthreads();

#pragma unroll 1
    for (int ch = 0; ch < C_ / CJ; ++ch) {
        // ---- issue next chunk's global loads EARLY (hide under compute) ----
        uint4 p0, p1, p2, p3;
        bool pf = (ch + 1 < C_ / CJ);
        if (pf) {
            const uint4* gh = (const uint4*)(khg + (size_t)(ch + 1) * CJ * D_);
            const uint4* gl = (const uint4*)(klg + (size_t)(ch + 1) * CJ * D_);
            p0 = gh[tid]; p1 = gh[tid + 256];
            p2 = gl[tid]; p3 = gl[tid + 256];
        }

        const u16* khc = smem + (ch & 1) * 2 * HBUF;
        const u16* klc = khc + HBUF;
        int jb = ch * CJ;

#pragma unroll
        for (int t = 0; t < 4; ++t) {      // 4 j-tiles of 16 cols
            const u16* bhp = &khc[(t * 16 + lm) * QP + lq * 8];
            const u16* blp = &klc[(t * 16 + lm) * QP + lq * 8];
            short8 bh0 = *(const short8*)bhp;
            short8 bh1 = *(const short8*)(bhp + 32);
            short8 bl0 = *(const short8*)blp;
            short8 bl1 = *(const short8*)(blp + 32);
            int rj = 1023 - (jb + t * 16 + lm);   // index packed desc

#pragma unroll
            for (int g = 0; g < 2; ++g) {
                f32x4 acc = {0.f, 0.f, 0.f, 0.f};
                acc = __builtin_amdgcn_mfma_f32_16x16x32_bf16(ahi[g][0], bh0, acc, 0, 0, 0);
                acc = __builtin_amdgcn_mfma_f32_16x16x32_bf16(ahi[g][1], bh1, acc, 0, 0, 0);
                acc = __builtin_amdgcn_mfma_f32_16x16x32_bf16(ahi[g][0], bl0, acc, 0, 0, 0);
                acc = __builtin_amdgcn_mfma_f32_16x16x32_bf16(ahi[g][1], bl1, acc, 0, 0, 0);
                acc = __builtin_amdgcn_mfma_f32_16x16x32_bf16(alo[g][0], bh0, acc, 0, 0, 0);
                acc = __builtin_amdgcn_mfma_f32_16x16x32_bf16(alo[g][1], bh1, acc, 0, 0, 0);
#pragma unroll
                for (int r = 0; r < 4; ++r) {
                    int pb = (__float_as_int(acc[r]) & 0xFFFFFC00) | rj;
                    float pv = __int_as_float(pb);
                    // top-2 update; invariant b1>=b2, no NaNs -> med3 is exact
                    b2[g][r] = __builtin_amdgcn_fmed3f(pv, b1[g][r], b2[g][r]);
                    b1[g][r] = fmaxf(pv, b1[g][r]);
                }
            }
        }

        // ---- write prefetched chunk into the other buffer, single barrier ----
        if (pf) {
            u16* wh = smem + ((ch + 1) & 1) * 2 * HBUF;
            u16* wl = wh + HBUF;
            *(uint4*)&wh[srow * QP + sc8]        = p0;
            *(uint4*)&wh[(srow + 32) * QP + sc8] = p1;
            *(uint4*)&wl[srow * QP + sc8]        = p2;
            *(uint4*)&wl[(srow + 32) * QP + sc8] = p3;
        }
        __syncthreads();
    }

    // ---- epilogue scratch in the (now free) LDS ----
    float* rv_f = (float*)smem;            // [TI][4] packed top-4 values
    int*   rj_i = (int*)(rv_f + TI * 4);   // [TI][4] decoded indices
    float* idxv = (float*)(rj_i + TI * 4); // [TI]
    float* sc_s = idxv + TI;               // [4]

    // ---- merge top-2 across the 16 lm-lanes -> row top-4, store to LDS ----
#pragma unroll
    for (int g = 0; g < 2; ++g)
#pragma unroll
    for (int r = 0; r < 4; ++r) {
        float e0 = b1[g][r], e1 = b2[g][r], e2 = -FLT_MAX, e3 = -FLT_MAX;
#pragma unroll
        for (int off = 1; off < 16; off <<= 1) {
            float e7 = __shfl_xor(e0, off, 16);
            float e6 = __shfl_xor(e1, off, 16);
            float e5 = __shfl_xor(e2, off, 16);
            float e4 = __shfl_xor(e3, off, 16);
            cf(e0, e4); cf(e1, e5); cf(e2, e6); cf(e3, e7);
            cf(e0, e2); cf(e1, e3); cf(e0, e1); cf(e2, e3);
        }
        if (lm == 0) {
            int rl = w * 32 + g * 16 + lq * 4 + r;
            int j0 = 1023 - (__float_as_int(e0) & 1023);
            rv_f[rl * 4 + 0] = e0; rj_i[rl * 4 + 0] = j0;
            rv_f[rl * 4 + 1] = e1; rj_i[rl * 4 + 1] = 1023 - (__float_as_int(e1) & 1023);
            rv_f[rl * 4 + 2] = e2; rj_i[rl * 4 + 2] = 1023 - (__float_as_int(e2) & 1023);
            rv_f[rl * 4 + 3] = e3; rj_i[rl * 4 + 3] = 1023 - (__float_as_int(e3) & 1023);
            idxv[rl] = (float)(j0 & (C_ - 1));
        }
    }
    __syncthreads();

    // ---- fused refine: numpy-fp32-emulated near-tie re-decision (verbatim
    // R5 logic: AVX512 16-lane accumulator, 4-unrolled chained FMA (chunk
    // order 3,2,1,0), _mm512_reduce_add_ps butterfly (strides 8,4,2,1)) ----
#pragma unroll 1
    for (int r = 0; r < TI; ++r) {
        float v0 = rv_f[r * 4 + 0];
        int nc = 1;
        while (nc < 4 && v0 - rv_f[r * 4 + nc] < EPS) ++nc;   // uniform across block
        if (nc == 1) continue;
        int wq = tid >> 6;
        int ln = tid & 63;
        if (wq < nc) {
            int j = rj_i[r * 4 + wq] & (C_ - 1);
            float qv = x[((size_t)(b * N_ + i0 + r)) * (H_ * D_) + h * D_ + ln] * 0.125f;
            float kv = k32[((size_t)h * C_ + j) * D_ + ln];
            float a2 = 0.f;
#pragma unroll
            for (int c = 3; c >= 0; --c) {
                float qq = __shfl(qv, (ln & 15) + c * 16, 64);
                float kk = __shfl(kv, (ln & 15) + c * 16, 64);
                a2 = fmaf(qq, kk, a2);
            }
#pragma unroll
            for (int off2 = 8; off2 >= 1; off2 >>= 1)
                a2 += __shfl_xor(a2, off2, 16);
            if (ln == 0) sc_s[wq] = a2;
        }
        __syncthreads();
        if (tid == 0) {
            float bs = sc_s[0]; int bj = rj_i[r * 4 + 0] & (C_ - 1);
            float ss = -FLT_MAX; int sj = bj;
            for (int k2 = 1; k2 < nc; ++k2) {
                float s = sc_s[k2]; int j = rj_i[r * 4 + k2] & (C_ - 1);
                if (s > bs || (s == bs && j < bj)) { ss = bs; sj = bj; bs = s; bj = j; }
                else if (s > ss || (s == ss && j < sj)) { ss = s; sj = j; }
            }
            rj_i[r * 4 + 0] = bj;
            float outv = (float)bj;
            int dj = bj > sj ? bj - sj : sj - bj;
            if (bs - ss < 1e-6f && dj <= 36 && dj > 0) outv = 0.5f * (float)(bj + sj);
            idxv[r] = outv;
        }
        __syncthreads();
    }
    __syncthreads();

    // ---- idx out + fused per-head histogram (same bucketing as perp) ----
    if (tid < TI) {
        float iv = idxv[tid];
        idx_out[(size_t)rowbase + tid] = iv;
        atomicAdd(&ghist[h * C_ + (((int)(iv + 0.25f)) & (C_ - 1))], 1u);
    }

    // ---- one-hot value gather -> out ----
    const float* vh = v32 + (size_t)h * C_ * D_;
    float* ob = out + ((size_t)(b * N_ + i0) * (H_ * D_)) + h * D_;
#pragma unroll
    for (int r = 0; r < TI / 4; ++r) {     // 32 iters: 4 rows per iteration
        int f   = tid + 256 * r;
        int row = f >> 6;
        int d   = f & 63;
        int bi  = rj_i[row * 4 + 0] & (C_ - 1);
        ob[(size_t)row * (H_ * D_) + d] = vh[(size_t)bi * D_ + d];
    }
}

// ---------------------------------------------------------------------------
// K3: perplexity per head from the fused global histogram. Same accumulation
// order (i = tid step 256) and same reduction tree as the verified version —
// counts are identical, so the result is bit-identical.
// ---------------------------------------------------------------------------
__global__ __launch_bounds__(256)
void perp_kernel(const u32* __restrict__ ghist, float* __restrict__ perp_out) {
    __shared__ float red[256];
    int h = blockIdx.x;
    int tid = threadIdx.x;

    float s = 0.f;
    for (int i = tid; i < C_; i += 256) {
        float p = (float)ghist[h * C_ + i] * (1.0f / (B_ * N_));
        s += p * logf(p + 1e-10f);
    }
    red[tid] = s;
    __syncthreads();
    for (int st = 128; st > 0; st >>= 1) {
        if (tid < st) red[tid] += red[tid + st];
        __syncthreads();
    }
    if (tid == 0) perp_out[h] = expf(-red[0]);
}

// ---------------------------------------------------------------------------
extern "C" void kernel_launch(void* const* d_in, const int* in_sizes, int n_in,
                              void* d_out, int out_size, void* d_ws, size_t ws_size,
                              hipStream_t stream) {
    (void)in_sizes; (void)n_in; (void)out_size; (void)ws_size;
    const float* x  = (const float*)d_in[0];   // (B, N, H*D) fp32
    const float* cb = (const float*)d_in[1];   // (H, C, D)   fp32
    const float* wk = (const float*)d_in[2];   // (H, D, D)   fp32
    const float* wv = (const float*)d_in[3];   // (H, D, D)   fp32

    // flat fp32 output buffer: [out | indices | perp]
    float* out      = (float*)d_out;                     // B*N*H*D
    float* idx_out  = out + (size_t)B_ * N_ * H_ * D_;   // B*H*N
    float* perp_out = idx_out + (size_t)B_ * H_ * N_;    // H

    // workspace: k32 4MiB | v32 4MiB | khi 2MiB | klo 2MiB | ghist 64KiB
    float* k32   = (float*)d_ws;
    float* v32   = k32 + (size_t)H_ * C_ * D_;
    u16*   khi   = (u16*)(v32 + (size_t)H_ * C_ * D_);
    u16*   klo   = khi + (size_t)H_ * C_ * D_;
    u32*   ghist = (u32*)(klo + (size_t)H_ * C_ * D_);

    proj_kernel<<<H_ * 32, 256, 0, stream>>>(cb, wk, wv, k32, v32, khi, klo, ghist);
    tile_kernel<<<B_ * H_ * (N_ / TI), 256, 0, stream>>>(x, khi, klo, k32, v32, ghist,
                                                         out, idx_out);
    perp_kernel<<<H_, 256, 0, stream>>>(ghist, perp_out);
}